// Round 5
// baseline (2604.878 us; speedup 1.0000x reference)
//
#include <hip/hip_runtime.h>
#include <hip/hip_bf16.h>

#define NEG_SLOPE 0.2f

// ------------------------------------------------------------ CSR build
__global__ void zero_int_k(int* __restrict__ p, int n) {
  int i = blockIdx.x * blockDim.x + threadIdx.x;
  if (i < n) p[i] = 0;
}

__global__ void deg_count_k(const int* __restrict__ dstA, int* __restrict__ deg, int E) {
  int e = blockIdx.x * blockDim.x + threadIdx.x;
  if (e < E) atomicAdd(&deg[dstA[e]], 1);
}

// exclusive scan, 3 phases (N <= 512*256)
__global__ void scan1_k(const int* __restrict__ deg, int* __restrict__ rowptr,
                        int* __restrict__ aux, int N) {
  __shared__ int sh[256];
  int t = threadIdx.x, i = blockIdx.x * 256 + t;
  int v = (i < N) ? deg[i] : 0;
  sh[t] = v; __syncthreads();
  for (int off = 1; off < 256; off <<= 1) {
    int x = (t >= off) ? sh[t - off] : 0;
    __syncthreads();
    sh[t] += x;
    __syncthreads();
  }
  if (i < N) rowptr[i] = sh[t] - v;          // exclusive within block
  if (t == 255) aux[blockIdx.x] = sh[255];   // block total
}

__global__ void scan2_k(int* __restrict__ aux, int naux) {
  __shared__ int sh[512];
  int t = threadIdx.x;
  int v = (t < naux) ? aux[t] : 0;
  sh[t] = v; __syncthreads();
  for (int off = 1; off < 512; off <<= 1) {
    int x = (t >= off) ? sh[t - off] : 0;
    __syncthreads();
    sh[t] += x;
    __syncthreads();
  }
  if (t < naux) aux[t] = sh[t] - v;          // exclusive block offsets
}

__global__ void scan3_k(int* __restrict__ rowptr, int* __restrict__ cursor,
                        const int* __restrict__ aux, int N, int E) {
  int i = blockIdx.x * blockDim.x + threadIdx.x;
  if (i < N) {
    int r = rowptr[i] + aux[i >> 8];
    rowptr[i] = r;
    cursor[i] = r;
  } else if (i == N) {
    rowptr[N] = E;
  }
}

__global__ void scatter_k(const int* __restrict__ srcA, const int* __restrict__ dstA,
                          int* __restrict__ cursor, int* __restrict__ csr_src,
                          int* __restrict__ csr_eid, int E) {
  int e = blockIdx.x * blockDim.x + threadIdx.x;
  if (e >= E) return;
  int pos = atomicAdd(&cursor[dstA[e]], 1);
  csr_src[pos] = srcA[e];
  csr_eid[pos] = e;
}

// ------------------------------------------------------------ self-loop attr (pull)
__global__ void loop_attr_k(const int* __restrict__ rowptr, const int* __restrict__ csr_eid,
                            const float* __restrict__ ea, float* __restrict__ loopA, int N) {
  int idx = blockIdx.x * blockDim.x + threadIdx.x;
  if (idx >= N * 16) return;
  int n = idx >> 4, c = idx & 15;
  int rs = rowptr[n], re = rowptr[n + 1];
  float sum = 0.f;
  for (int i = rs; i < re; ++i) sum += ea[(size_t)csr_eid[i] * 16 + c];
  loopA[idx] = sum / fmaxf((float)(re - rs), 1.f);
}

// ------------------------------------------------- layer1 node transform (128 -> 64|64)
// 256 thr: col = t&127 (col<64 -> xl, col>=64 -> xr), grp = t>>7 owns 8 of 16 tile nodes.
// wT in LDS transposed w/ stride 132 for conflict-free b128; xs reads are broadcasts.
__global__ __launch_bounds__(256) void transform1_k(
    const float* __restrict__ x, const float* __restrict__ wl, const float* __restrict__ wr,
    float* __restrict__ xl, float* __restrict__ xr, int N) {
  __shared__ float wT[128 * 132];     // 67584 B
  __shared__ float xs[16 * 128];      // 8192 B
  int t = threadIdx.x;
  for (int i = t; i < 128 * 64; i += 256) {
    int k = i >> 6, j = i & 63;
    wT[j * 132 + k]        = wl[i];   // i == k*64+j
    wT[(j + 64) * 132 + k] = wr[i];
  }
  __syncthreads();
  int col = t & 127;
  int grp = t >> 7;                   // 0 or 1
  int ntiles = (N + 15) >> 4;
  for (int tile = blockIdx.x; tile < ntiles; tile += gridDim.x) {
    int base = tile << 4;
    // stage 16 node rows (2048 floats = 512 float4)
    const float4* x4 = (const float4*)x;
    float4* xs4 = (float4*)xs;
    for (int i = t; i < 512; i += 256) {
      int node = base + (i >> 5);     // 32 float4 per node
      float4 v = {0.f, 0.f, 0.f, 0.f};
      if (node < N) v = x4[(size_t)node * 32 + (i & 31)];
      xs4[i] = v;
    }
    __syncthreads();
    float acc[8] = {0.f, 0.f, 0.f, 0.f, 0.f, 0.f, 0.f, 0.f};
#pragma unroll
    for (int k4 = 0; k4 < 32; ++k4) {
      float4 w = *(const float4*)&wT[col * 132 + k4 * 4];
#pragma unroll
      for (int i = 0; i < 8; ++i) {
        float4 xv = *(const float4*)&xs[(grp * 8 + i) * 128 + k4 * 4];
        acc[i] += w.x * xv.x + w.y * xv.y + w.z * xv.z + w.w * xv.w;
      }
    }
    float* dp = (col < 64) ? xl : xr;
    int j = col & 63;
#pragma unroll
    for (int i = 0; i < 8; ++i) {
      int node = base + grp * 8 + i;
      if (node < N) dp[(size_t)node * 64 + j] = acc[i];
    }
    __syncthreads();
  }
}

// ------------------------------------------------- layer2 node transform (64 -> 32|32)
// 256 thr: col = t&63, grp = t>>6 owns 8 of 32 tile nodes.
__global__ __launch_bounds__(256) void transform2_k(
    const float* __restrict__ h, const float* __restrict__ wl, const float* __restrict__ wr,
    float* __restrict__ xl, float* __restrict__ xr, int N) {
  __shared__ float wT[64 * 68];       // 17408 B
  __shared__ float xs[32 * 64];       // 8192 B
  int t = threadIdx.x;
  for (int i = t; i < 64 * 32; i += 256) {
    int k = i >> 5, j = i & 31;
    wT[j * 68 + k]        = wl[i];    // i == k*32+j
    wT[(j + 32) * 68 + k] = wr[i];
  }
  __syncthreads();
  int col = t & 63;
  int grp = t >> 6;                   // 0..3
  int ntiles = (N + 31) >> 5;
  for (int tile = blockIdx.x; tile < ntiles; tile += gridDim.x) {
    int base = tile << 5;
    const float4* h4 = (const float4*)h;
    float4* xs4 = (float4*)xs;
    for (int i = t; i < 512; i += 256) {
      int node = base + (i >> 4);     // 16 float4 per node
      float4 v = {0.f, 0.f, 0.f, 0.f};
      if (node < N) v = h4[(size_t)node * 16 + (i & 15)];
      xs4[i] = v;
    }
    __syncthreads();
    float acc[8] = {0.f, 0.f, 0.f, 0.f, 0.f, 0.f, 0.f, 0.f};
#pragma unroll
    for (int k4 = 0; k4 < 16; ++k4) {
      float4 w = *(const float4*)&wT[col * 68 + k4 * 4];
#pragma unroll
      for (int i = 0; i < 8; ++i) {
        float4 xv = *(const float4*)&xs[(grp * 8 + i) * 64 + k4 * 4];
        acc[i] += w.x * xv.x + w.y * xv.y + w.z * xv.z + w.w * xv.w;
      }
    }
    float* dp = (col < 32) ? xl : xr;
    int j = col & 31;
#pragma unroll
    for (int i = 0; i < 8; ++i) {
      int node = base + grp * 8 + i;
      if (node < N) dp[(size_t)node * 32 + j] = acc[i];
    }
    __syncthreads();
  }
}

// ------------------------------------------------- GAT layer1: one wave per node (pull)
__global__ __launch_bounds__(256) void gat1_k(
    const int* __restrict__ rowptr, const int* __restrict__ csr_src,
    const int* __restrict__ csr_eid, const float* __restrict__ ea,
    const float* __restrict__ loopA, const float* __restrict__ we,
    const float* __restrict__ att, const float* __restrict__ b,
    const float* __restrict__ xl, const float* __restrict__ xr,
    float* __restrict__ h, int N) {
  __shared__ float weS[16 * 64];
  __shared__ float attS[64];
  __shared__ float bS[64];
  int t = threadIdx.x;
  for (int i = t; i < 16 * 64; i += 256) weS[i] = we[i];
  if (t < 64) { attS[t] = att[t]; bS[t] = b[t]; }
  __syncthreads();
  int lane = t & 63;
  int wid = (blockIdx.x * blockDim.x + t) >> 6;
  int nwaves = (gridDim.x * blockDim.x) >> 6;
  for (int n = wid; n < N; n += nwaves) {
    float xr_v = xr[(size_t)n * 64 + lane];
    float xl_s = xl[(size_t)n * 64 + lane];
    // self loop
    const float4* lp4 = (const float4*)(loopA + (size_t)n * 16);
    float4 l0 = lp4[0], l1 = lp4[1], l2 = lp4[2], l3 = lp4[3];
    float ef = l0.x * weS[0 * 64 + lane] + l0.y * weS[1 * 64 + lane] +
               l0.z * weS[2 * 64 + lane] + l0.w * weS[3 * 64 + lane] +
               l1.x * weS[4 * 64 + lane] + l1.y * weS[5 * 64 + lane] +
               l1.z * weS[6 * 64 + lane] + l1.w * weS[7 * 64 + lane] +
               l2.x * weS[8 * 64 + lane] + l2.y * weS[9 * 64 + lane] +
               l2.z * weS[10 * 64 + lane] + l2.w * weS[11 * 64 + lane] +
               l3.x * weS[12 * 64 + lane] + l3.y * weS[13 * 64 + lane] +
               l3.z * weS[14 * 64 + lane] + l3.w * weS[15 * 64 + lane];
    float m = xl_s + xr_v + ef;
    m = (m > 0.f) ? m : NEG_SLOPE * m;
    float sc = m * attS[lane];
#pragma unroll
    for (int off = 1; off < 32; off <<= 1) sc += __shfl_xor(sc, off);
    float ex = __expf(sc);
    float num = ex * xl_s;
    float den = ex;
    int rs = rowptr[n], re = rowptr[n + 1];
    for (int base = rs; base < re; base += 64) {
      int cnt = min(64, re - base);
      int s_l = 0, e_l = 0;
      if (lane < cnt) { s_l = csr_src[base + lane]; e_l = csr_eid[base + lane]; }
      for (int i = 0; i < cnt; ++i) {
        int s = __shfl(s_l, i);
        int eid = __shfl(e_l, i);
        float xlv = xl[(size_t)s * 64 + lane];
        const float4* e4 = (const float4*)(ea + (size_t)eid * 16);
        float4 a0 = e4[0], a1 = e4[1], a2 = e4[2], a3 = e4[3];
        float ef2 = a0.x * weS[0 * 64 + lane] + a0.y * weS[1 * 64 + lane] +
                    a0.z * weS[2 * 64 + lane] + a0.w * weS[3 * 64 + lane] +
                    a1.x * weS[4 * 64 + lane] + a1.y * weS[5 * 64 + lane] +
                    a1.z * weS[6 * 64 + lane] + a1.w * weS[7 * 64 + lane] +
                    a2.x * weS[8 * 64 + lane] + a2.y * weS[9 * 64 + lane] +
                    a2.z * weS[10 * 64 + lane] + a2.w * weS[11 * 64 + lane] +
                    a3.x * weS[12 * 64 + lane] + a3.y * weS[13 * 64 + lane] +
                    a3.z * weS[14 * 64 + lane] + a3.w * weS[15 * 64 + lane];
        float mm = xlv + xr_v + ef2;
        mm = (mm > 0.f) ? mm : NEG_SLOPE * mm;
        float s2 = mm * attS[lane];
#pragma unroll
        for (int off = 1; off < 32; off <<= 1) s2 += __shfl_xor(s2, off);
        float e2 = __expf(s2);
        num += e2 * xlv;
        den += e2;
      }
    }
    h[(size_t)n * 64 + lane] = fmaxf(num / fmaxf(den, 1e-16f) + bS[lane], 0.f);
  }
}

// ------------------------------------------------- GAT layer2: half-wave per node
__global__ __launch_bounds__(256) void gat2_k(
    const int* __restrict__ rowptr, const int* __restrict__ csr_src,
    const int* __restrict__ csr_eid, const float* __restrict__ ea,
    const float* __restrict__ loopA, const float* __restrict__ we,
    const float* __restrict__ att, const float* __restrict__ b,
    const float* __restrict__ xl, const float* __restrict__ xr,
    float* __restrict__ h, int N) {
  __shared__ float weS[16 * 32];
  __shared__ float attS[32];
  __shared__ float bS[32];
  int t = threadIdx.x;
  for (int i = t; i < 16 * 32; i += 256) weS[i] = we[i];
  if (t < 32) { attS[t] = att[t]; bS[t] = b[t]; }
  __syncthreads();
  int lane = t & 63;
  int c = lane & 31;
  int half = lane >> 5;               // 0 or 1: which node of the pair
  int hbase = lane & 32;              // shfl base of own half
  int wid = (blockIdx.x * blockDim.x + t) >> 6;
  int nwaves = (gridDim.x * blockDim.x) >> 6;
  for (int np = wid; np * 2 < N; np += nwaves) {
    int n = np * 2 + half;
    if (n >= N) continue;             // whole half exits together
    float xr_v = xr[(size_t)n * 32 + c];
    float xl_s = xl[(size_t)n * 32 + c];
    const float4* lp4 = (const float4*)(loopA + (size_t)n * 16);
    float4 l0 = lp4[0], l1 = lp4[1], l2 = lp4[2], l3 = lp4[3];
    float ef = l0.x * weS[0 * 32 + c] + l0.y * weS[1 * 32 + c] +
               l0.z * weS[2 * 32 + c] + l0.w * weS[3 * 32 + c] +
               l1.x * weS[4 * 32 + c] + l1.y * weS[5 * 32 + c] +
               l1.z * weS[6 * 32 + c] + l1.w * weS[7 * 32 + c] +
               l2.x * weS[8 * 32 + c] + l2.y * weS[9 * 32 + c] +
               l2.z * weS[10 * 32 + c] + l2.w * weS[11 * 32 + c] +
               l3.x * weS[12 * 32 + c] + l3.y * weS[13 * 32 + c] +
               l3.z * weS[14 * 32 + c] + l3.w * weS[15 * 32 + c];
    float m = xl_s + xr_v + ef;
    m = (m > 0.f) ? m : NEG_SLOPE * m;
    float sc = m * attS[c];
#pragma unroll
    for (int off = 1; off < 32; off <<= 1) sc += __shfl_xor(sc, off);
    float ex = __expf(sc);
    float num = ex * xl_s;
    float den = ex;
    int rs = rowptr[n], re = rowptr[n + 1];
    for (int base = rs; base < re; base += 32) {
      int cnt = min(32, re - base);
      int s_l = 0, e_l = 0;
      if (c < cnt) { s_l = csr_src[base + c]; e_l = csr_eid[base + c]; }
      for (int i = 0; i < cnt; ++i) {
        int s = __shfl(s_l, hbase + i);
        int eid = __shfl(e_l, hbase + i);
        float xlv = xl[(size_t)s * 32 + c];
        const float4* e4 = (const float4*)(ea + (size_t)eid * 16);
        float4 a0 = e4[0], a1 = e4[1], a2 = e4[2], a3 = e4[3];
        float ef2 = a0.x * weS[0 * 32 + c] + a0.y * weS[1 * 32 + c] +
                    a0.z * weS[2 * 32 + c] + a0.w * weS[3 * 32 + c] +
                    a1.x * weS[4 * 32 + c] + a1.y * weS[5 * 32 + c] +
                    a1.z * weS[6 * 32 + c] + a1.w * weS[7 * 32 + c] +
                    a2.x * weS[8 * 32 + c] + a2.y * weS[9 * 32 + c] +
                    a2.z * weS[10 * 32 + c] + a2.w * weS[11 * 32 + c] +
                    a3.x * weS[12 * 32 + c] + a3.y * weS[13 * 32 + c] +
                    a3.z * weS[14 * 32 + c] + a3.w * weS[15 * 32 + c];
        float mm = xlv + xr_v + ef2;
        mm = (mm > 0.f) ? mm : NEG_SLOPE * mm;
        float s2 = mm * attS[c];
#pragma unroll
        for (int off = 1; off < 32; off <<= 1) s2 += __shfl_xor(s2, off);
        float e2 = __expf(s2);
        num += e2 * xlv;
        den += e2;
      }
    }
    h[(size_t)n * 32 + c] = fmaxf(num / fmaxf(den, 1e-16f) + bS[c], 0.f);
  }
}

// ------------------------------------------------- fused mean-pool + fc
// batch is SORTED -> graph g owns a contiguous node range; one block per graph.
__global__ __launch_bounds__(256) void pool_fc_k(
    const float* __restrict__ h, const int* __restrict__ batch,
    const float* __restrict__ wfc, const float* __restrict__ bfc,
    float* __restrict__ out, int N) {
  int g = blockIdx.x;
  __shared__ int srange[2];
  __shared__ float part[8][32];
  int t = threadIdx.x;
  if (t < 2) {
    int key = g + t;                  // t==0: lower_bound(g), t==1: lower_bound(g+1)
    int lo = 0, hi = N;
    while (lo < hi) { int mid = (lo + hi) >> 1; if (batch[mid] < key) lo = mid + 1; else hi = mid; }
    srange[t] = lo;
  }
  __syncthreads();
  int rs = srange[0], re = srange[1];
  int c = t & 31, sub = t >> 5;       // 8 sub-groups of 32 channels
  float acc = 0.f;
  for (int n = rs + sub; n < re; n += 8) acc += h[(size_t)n * 32 + c];
  part[sub][c] = acc;
  __syncthreads();
  if (sub == 0) {
    float s = part[0][c];
#pragma unroll
    for (int i = 1; i < 8; ++i) s += part[i][c];
    part[0][c] = s / fmaxf((float)(re - rs), 1.f);
  }
  __syncthreads();
  if (sub == 0) {
    float a = 0.f;
#pragma unroll
    for (int k = 0; k < 32; ++k) a += part[0][k] * wfc[k * 32 + c];
    out[g * 32 + c] = a + bfc[c];
  }
}

// ----------------------------------------------------------------- launcher
extern "C" void kernel_launch(void* const* d_in, const int* in_sizes, int n_in,
                              void* d_out, int out_size, void* d_ws, size_t ws_size,
                              hipStream_t stream) {
  const float* x   = (const float*)d_in[0];
  const int*   ei  = (const int*)d_in[1];
  const float* ea  = (const float*)d_in[2];
  const int*   bat = (const int*)d_in[3];
  const float* wl1 = (const float*)d_in[4];
  const float* wr1 = (const float*)d_in[5];
  const float* we1 = (const float*)d_in[6];
  const float* at1 = (const float*)d_in[7];
  const float* b1  = (const float*)d_in[8];
  const float* wl2 = (const float*)d_in[9];
  const float* wr2 = (const float*)d_in[10];
  const float* we2 = (const float*)d_in[11];
  const float* at2 = (const float*)d_in[12];
  const float* b2  = (const float*)d_in[13];
  const float* wfc = (const float*)d_in[14];
  const float* bfc = (const float*)d_in[15];

  const int N = in_sizes[0] / 128;
  const int E = in_sizes[1] / 2;
  const int G = 256;
  const int* srcA = ei;
  const int* dstA = ei + E;

  // ---- workspace layout (~72 MB) ----
  int* deg      = (int*)d_ws;                  // N
  int* rowptr   = deg + N;                     // N+1
  int* cursor   = rowptr + (N + 1);            // N
  int* aux      = cursor + N;                  // 512
  int* csr_src  = aux + 512;                   // E
  int* csr_eid  = csr_src + E;                 // E
  float* loopA  = (float*)(csr_eid + E);       // N*16
  float* xl1    = loopA + (size_t)N * 16;      // N*64
  float* xr1    = xl1 + (size_t)N * 64;        // N*64
  float* h1     = xr1;                         // in-place over xr1
  float* xl2    = xl1;                         // N*32 (xl1 dead after gat1)
  float* xr2    = xl1 + (size_t)N * 32;        // N*32
  float* h2     = xr2;                         // in-place over xr2

  const int naux = (N + 255) / 256;

  // ---- CSR build ----
  zero_int_k<<<(N + 255) / 256, 256, 0, stream>>>(deg, N);
  deg_count_k<<<(E + 255) / 256, 256, 0, stream>>>(dstA, deg, E);
  scan1_k<<<naux, 256, 0, stream>>>(deg, rowptr, aux, N);
  scan2_k<<<1, 512, 0, stream>>>(aux, naux);
  scan3_k<<<(N + 256) / 256, 256, 0, stream>>>(rowptr, cursor, aux, N, E);
  scatter_k<<<(E + 255) / 256, 256, 0, stream>>>(srcA, dstA, cursor, csr_src, csr_eid, E);

  // ---- self-loop attrs ----
  loop_attr_k<<<(N * 16 + 255) / 256, 256, 0, stream>>>(rowptr, csr_eid, ea, loopA, N);

  // ---- layer 1 ----
  transform1_k<<<2048, 256, 0, stream>>>(x, wl1, wr1, xl1, xr1, N);
  gat1_k<<<8192, 256, 0, stream>>>(rowptr, csr_src, csr_eid, ea, loopA, we1, at1, b1,
                                   xl1, xr1, h1, N);

  // ---- layer 2 ----
  transform2_k<<<1024, 256, 0, stream>>>(h1, wl2, wr2, xl2, xr2, N);
  gat2_k<<<8192, 256, 0, stream>>>(rowptr, csr_src, csr_eid, ea, loopA, we2, at2, b2,
                                   xl2, xr2, h2, N);

  // ---- fused pool + fc ----
  pool_fc_k<<<G, 256, 0, stream>>>(h2, bat, wfc, bfc, (float*)d_out, N);
}

// Round 6
// 709.638 us; speedup vs baseline: 3.6707x; 3.6707x over previous
//
#include <hip/hip_runtime.h>
#include <hip/hip_bf16.h>

#define NEG_SLOPE 0.2f

// ------------------------------------------------------------ CSR build
__global__ void zero_int_k(int* __restrict__ p, int n) {
  int i = blockIdx.x * blockDim.x + threadIdx.x;
  if (i < n) p[i] = 0;
}

__global__ void deg_count_k(const int* __restrict__ dstA, int* __restrict__ deg, int E) {
  int e = blockIdx.x * blockDim.x + threadIdx.x;
  if (e < E) atomicAdd(&deg[dstA[e]], 1);
}

// exclusive scan, 3 phases (N <= 512*256)
__global__ void scan1_k(const int* __restrict__ deg, int* __restrict__ rowptr,
                        int* __restrict__ aux, int N) {
  __shared__ int sh[256];
  int t = threadIdx.x, i = blockIdx.x * 256 + t;
  int v = (i < N) ? deg[i] : 0;
  sh[t] = v; __syncthreads();
  for (int off = 1; off < 256; off <<= 1) {
    int x = (t >= off) ? sh[t - off] : 0;
    __syncthreads();
    sh[t] += x;
    __syncthreads();
  }
  if (i < N) rowptr[i] = sh[t] - v;          // exclusive within block
  if (t == 255) aux[blockIdx.x] = sh[255];   // block total
}

__global__ void scan2_k(int* __restrict__ aux, int naux) {
  __shared__ int sh[512];
  int t = threadIdx.x;
  int v = (t < naux) ? aux[t] : 0;
  sh[t] = v; __syncthreads();
  for (int off = 1; off < 512; off <<= 1) {
    int x = (t >= off) ? sh[t - off] : 0;
    __syncthreads();
    sh[t] += x;
    __syncthreads();
  }
  if (t < naux) aux[t] = sh[t] - v;          // exclusive block offsets
}

__global__ void scan3_k(int* __restrict__ rowptr, int* __restrict__ cursor,
                        const int* __restrict__ aux, int N, int E) {
  int i = blockIdx.x * blockDim.x + threadIdx.x;
  if (i < N) {
    int r = rowptr[i] + aux[i >> 8];
    rowptr[i] = r;
    cursor[i] = r;
  } else if (i == N) {
    rowptr[N] = E;
  }
}

__global__ void scatter_k(const int* __restrict__ srcA, const int* __restrict__ dstA,
                          int* __restrict__ cursor, int* __restrict__ csr_src,
                          int* __restrict__ csr_eid, int E) {
  int e = blockIdx.x * blockDim.x + threadIdx.x;
  if (e >= E) return;
  int pos = atomicAdd(&cursor[dstA[e]], 1);
  csr_src[pos] = srcA[e];
  csr_eid[pos] = e;
}

// ------------------------------------------------------------ self-loop attr (pull)
__global__ void loop_attr_k(const int* __restrict__ rowptr, const int* __restrict__ csr_eid,
                            const float* __restrict__ ea, float* __restrict__ loopA, int N) {
  int idx = blockIdx.x * blockDim.x + threadIdx.x;
  if (idx >= N * 16) return;
  int n = idx >> 4, c = idx & 15;
  int rs = rowptr[n], re = rowptr[n + 1];
  float sum = 0.f;
  for (int i = rs; i < re; ++i) sum += ea[(size_t)csr_eid[i] * 16 + c];
  loopA[idx] = sum / fmaxf((float)(re - rs), 1.f);
}

// ------------------------------------------------- layer1 node transform (128 -> 64|64)
// W in LDS NATURAL [k][col] layout; per k: one float4 W read + broadcast x scalar.
// tc = t&31 owns cols tc*4..+3 (of 128); tr = t>>5 owns nodes tr*4..+3 (32-node tile).
// acc = 4x float4 (16 regs); unroll capped to avoid the round-5 spill.
__global__ __launch_bounds__(256) void transform1_k(
    const float* __restrict__ x, const float* __restrict__ wl, const float* __restrict__ wr,
    float* __restrict__ xl, float* __restrict__ xr, int N) {
  __shared__ float wS[128 * 128];     // 64 KB, [k][col]: col<64 wl, col>=64 wr
  __shared__ float xs[32 * 128];      // 16 KB, [node][k]
  int t = threadIdx.x;
  for (int i = t; i < 128 * 64; i += 256) {
    int k = i >> 6, j = i & 63;
    wS[k * 128 + j]      = wl[i];     // i == k*64+j
    wS[k * 128 + 64 + j] = wr[i];
  }
  __syncthreads();
  int tc = t & 31;
  int tr = t >> 5;
  int ntiles = (N + 31) >> 5;
  for (int tile = blockIdx.x; tile < ntiles; tile += gridDim.x) {
    int base = tile << 5;
    const float4* x4 = (const float4*)x;
    float4* xs4 = (float4*)xs;
    for (int i = t; i < 1024; i += 256) {          // 32 nodes * 32 float4
      int node = base + (i >> 5);
      float4 v = {0.f, 0.f, 0.f, 0.f};
      if (node < N) v = x4[(size_t)node * 32 + (i & 31)];
      xs4[i] = v;
    }
    __syncthreads();
    float4 acc0 = {0,0,0,0}, acc1 = {0,0,0,0}, acc2 = {0,0,0,0}, acc3 = {0,0,0,0};
    const float* xrow = &xs[tr * 4 * 128];
#pragma unroll 4
    for (int k = 0; k < 128; ++k) {
      float4 w4 = *(const float4*)&wS[k * 128 + tc * 4];
      float x0 = xrow[k], x1 = xrow[128 + k], x2 = xrow[256 + k], x3 = xrow[384 + k];
      acc0.x += x0 * w4.x; acc0.y += x0 * w4.y; acc0.z += x0 * w4.z; acc0.w += x0 * w4.w;
      acc1.x += x1 * w4.x; acc1.y += x1 * w4.y; acc1.z += x1 * w4.z; acc1.w += x1 * w4.w;
      acc2.x += x2 * w4.x; acc2.y += x2 * w4.y; acc2.z += x2 * w4.z; acc2.w += x2 * w4.w;
      acc3.x += x3 * w4.x; acc3.y += x3 * w4.y; acc3.z += x3 * w4.z; acc3.w += x3 * w4.w;
    }
    float* dp = (tc < 16) ? xl : xr;
    int j4 = (tc & 15) * 4;
    int nb = base + tr * 4;
    if (nb + 0 < N) *(float4*)&dp[(size_t)(nb + 0) * 64 + j4] = acc0;
    if (nb + 1 < N) *(float4*)&dp[(size_t)(nb + 1) * 64 + j4] = acc1;
    if (nb + 2 < N) *(float4*)&dp[(size_t)(nb + 2) * 64 + j4] = acc2;
    if (nb + 3 < N) *(float4*)&dp[(size_t)(nb + 3) * 64 + j4] = acc3;
    __syncthreads();
  }
}

// ------------------------------------------------- layer2 node transform (64 -> 32|32)
// tc = t&15 owns cols tc*4..+3 (of 64); tr = t>>4 owns nodes tr*4..+3 (64-node tile).
__global__ __launch_bounds__(256) void transform2_k(
    const float* __restrict__ h, const float* __restrict__ wl, const float* __restrict__ wr,
    float* __restrict__ xl, float* __restrict__ xr, int N) {
  __shared__ float wS[64 * 64];       // 16 KB, [k][col]: col<32 wl, col>=32 wr
  __shared__ float xs[64 * 64];       // 16 KB, [node][k]
  int t = threadIdx.x;
  for (int i = t; i < 64 * 32; i += 256) {
    int k = i >> 5, j = i & 31;
    wS[k * 64 + j]      = wl[i];      // i == k*32+j
    wS[k * 64 + 32 + j] = wr[i];
  }
  __syncthreads();
  int tc = t & 15;
  int tr = t >> 4;
  int ntiles = (N + 63) >> 6;
  for (int tile = blockIdx.x; tile < ntiles; tile += gridDim.x) {
    int base = tile << 6;
    const float4* h4 = (const float4*)h;
    float4* xs4 = (float4*)xs;
    for (int i = t; i < 1024; i += 256) {          // 64 nodes * 16 float4
      int node = base + (i >> 4);
      float4 v = {0.f, 0.f, 0.f, 0.f};
      if (node < N) v = h4[(size_t)node * 16 + (i & 15)];
      xs4[i] = v;
    }
    __syncthreads();
    float4 acc0 = {0,0,0,0}, acc1 = {0,0,0,0}, acc2 = {0,0,0,0}, acc3 = {0,0,0,0};
    const float* xrow = &xs[tr * 4 * 64];
#pragma unroll 4
    for (int k = 0; k < 64; ++k) {
      float4 w4 = *(const float4*)&wS[k * 64 + tc * 4];
      float x0 = xrow[k], x1 = xrow[64 + k], x2 = xrow[128 + k], x3 = xrow[192 + k];
      acc0.x += x0 * w4.x; acc0.y += x0 * w4.y; acc0.z += x0 * w4.z; acc0.w += x0 * w4.w;
      acc1.x += x1 * w4.x; acc1.y += x1 * w4.y; acc1.z += x1 * w4.z; acc1.w += x1 * w4.w;
      acc2.x += x2 * w4.x; acc2.y += x2 * w4.y; acc2.z += x2 * w4.z; acc2.w += x2 * w4.w;
      acc3.x += x3 * w4.x; acc3.y += x3 * w4.y; acc3.z += x3 * w4.z; acc3.w += x3 * w4.w;
    }
    float* dp = (tc < 8) ? xl : xr;
    int j4 = (tc & 7) * 4;
    int nb = base + tr * 4;
    if (nb + 0 < N) *(float4*)&dp[(size_t)(nb + 0) * 32 + j4] = acc0;
    if (nb + 1 < N) *(float4*)&dp[(size_t)(nb + 1) * 32 + j4] = acc1;
    if (nb + 2 < N) *(float4*)&dp[(size_t)(nb + 2) * 32 + j4] = acc2;
    if (nb + 3 < N) *(float4*)&dp[(size_t)(nb + 3) * 32 + j4] = acc3;
    __syncthreads();
  }
}

// ------------------------------------------------- GAT layer1: one wave per node (pull)
__global__ __launch_bounds__(256) void gat1_k(
    const int* __restrict__ rowptr, const int* __restrict__ csr_src,
    const int* __restrict__ csr_eid, const float* __restrict__ ea,
    const float* __restrict__ loopA, const float* __restrict__ we,
    const float* __restrict__ att, const float* __restrict__ b,
    const float* __restrict__ xl, const float* __restrict__ xr,
    float* __restrict__ h, int N) {
  __shared__ float weS[16 * 64];
  __shared__ float attS[64];
  __shared__ float bS[64];
  int t = threadIdx.x;
  for (int i = t; i < 16 * 64; i += 256) weS[i] = we[i];
  if (t < 64) { attS[t] = att[t]; bS[t] = b[t]; }
  __syncthreads();
  int lane = t & 63;
  int wid = (blockIdx.x * blockDim.x + t) >> 6;
  int nwaves = (gridDim.x * blockDim.x) >> 6;
  for (int n = wid; n < N; n += nwaves) {
    float xr_v = xr[(size_t)n * 64 + lane];
    float xl_s = xl[(size_t)n * 64 + lane];
    // self loop
    const float4* lp4 = (const float4*)(loopA + (size_t)n * 16);
    float4 l0 = lp4[0], l1 = lp4[1], l2 = lp4[2], l3 = lp4[3];
    float ef = l0.x * weS[0 * 64 + lane] + l0.y * weS[1 * 64 + lane] +
               l0.z * weS[2 * 64 + lane] + l0.w * weS[3 * 64 + lane] +
               l1.x * weS[4 * 64 + lane] + l1.y * weS[5 * 64 + lane] +
               l1.z * weS[6 * 64 + lane] + l1.w * weS[7 * 64 + lane] +
               l2.x * weS[8 * 64 + lane] + l2.y * weS[9 * 64 + lane] +
               l2.z * weS[10 * 64 + lane] + l2.w * weS[11 * 64 + lane] +
               l3.x * weS[12 * 64 + lane] + l3.y * weS[13 * 64 + lane] +
               l3.z * weS[14 * 64 + lane] + l3.w * weS[15 * 64 + lane];
    float m = xl_s + xr_v + ef;
    m = (m > 0.f) ? m : NEG_SLOPE * m;
    float sc = m * attS[lane];
#pragma unroll
    for (int off = 1; off < 32; off <<= 1) sc += __shfl_xor(sc, off);
    float ex = __expf(sc);
    float num = ex * xl_s;
    float den = ex;
    int rs = rowptr[n], re = rowptr[n + 1];
    for (int base = rs; base < re; base += 64) {
      int cnt = min(64, re - base);
      int s_l = 0, e_l = 0;
      if (lane < cnt) { s_l = csr_src[base + lane]; e_l = csr_eid[base + lane]; }
      for (int i = 0; i < cnt; ++i) {
        int s = __shfl(s_l, i);
        int eid = __shfl(e_l, i);
        float xlv = xl[(size_t)s * 64 + lane];
        const float4* e4 = (const float4*)(ea + (size_t)eid * 16);
        float4 a0 = e4[0], a1 = e4[1], a2 = e4[2], a3 = e4[3];
        float ef2 = a0.x * weS[0 * 64 + lane] + a0.y * weS[1 * 64 + lane] +
                    a0.z * weS[2 * 64 + lane] + a0.w * weS[3 * 64 + lane] +
                    a1.x * weS[4 * 64 + lane] + a1.y * weS[5 * 64 + lane] +
                    a1.z * weS[6 * 64 + lane] + a1.w * weS[7 * 64 + lane] +
                    a2.x * weS[8 * 64 + lane] + a2.y * weS[9 * 64 + lane] +
                    a2.z * weS[10 * 64 + lane] + a2.w * weS[11 * 64 + lane] +
                    a3.x * weS[12 * 64 + lane] + a3.y * weS[13 * 64 + lane] +
                    a3.z * weS[14 * 64 + lane] + a3.w * weS[15 * 64 + lane];
        float mm = xlv + xr_v + ef2;
        mm = (mm > 0.f) ? mm : NEG_SLOPE * mm;
        float s2 = mm * attS[lane];
#pragma unroll
        for (int off = 1; off < 32; off <<= 1) s2 += __shfl_xor(s2, off);
        float e2 = __expf(s2);
        num += e2 * xlv;
        den += e2;
      }
    }
    h[(size_t)n * 64 + lane] = fmaxf(num / fmaxf(den, 1e-16f) + bS[lane], 0.f);
  }
}

// ------------------------------------------------- GAT layer2: half-wave per node
__global__ __launch_bounds__(256) void gat2_k(
    const int* __restrict__ rowptr, const int* __restrict__ csr_src,
    const int* __restrict__ csr_eid, const float* __restrict__ ea,
    const float* __restrict__ loopA, const float* __restrict__ we,
    const float* __restrict__ att, const float* __restrict__ b,
    const float* __restrict__ xl, const float* __restrict__ xr,
    float* __restrict__ h, int N) {
  __shared__ float weS[16 * 32];
  __shared__ float attS[32];
  __shared__ float bS[32];
  int t = threadIdx.x;
  for (int i = t; i < 16 * 32; i += 256) weS[i] = we[i];
  if (t < 32) { attS[t] = att[t]; bS[t] = b[t]; }
  __syncthreads();
  int lane = t & 63;
  int c = lane & 31;
  int half = lane >> 5;               // 0 or 1: which node of the pair
  int hbase = lane & 32;              // shfl base of own half
  int wid = (blockIdx.x * blockDim.x + t) >> 6;
  int nwaves = (gridDim.x * blockDim.x) >> 6;
  for (int np = wid; np * 2 < N; np += nwaves) {
    int n = np * 2 + half;
    if (n >= N) continue;             // whole half exits together
    float xr_v = xr[(size_t)n * 32 + c];
    float xl_s = xl[(size_t)n * 32 + c];
    const float4* lp4 = (const float4*)(loopA + (size_t)n * 16);
    float4 l0 = lp4[0], l1 = lp4[1], l2 = lp4[2], l3 = lp4[3];
    float ef = l0.x * weS[0 * 32 + c] + l0.y * weS[1 * 32 + c] +
               l0.z * weS[2 * 32 + c] + l0.w * weS[3 * 32 + c] +
               l1.x * weS[4 * 32 + c] + l1.y * weS[5 * 32 + c] +
               l1.z * weS[6 * 32 + c] + l1.w * weS[7 * 32 + c] +
               l2.x * weS[8 * 32 + c] + l2.y * weS[9 * 32 + c] +
               l2.z * weS[10 * 32 + c] + l2.w * weS[11 * 32 + c] +
               l3.x * weS[12 * 32 + c] + l3.y * weS[13 * 32 + c] +
               l3.z * weS[14 * 32 + c] + l3.w * weS[15 * 32 + c];
    float m = xl_s + xr_v + ef;
    m = (m > 0.f) ? m : NEG_SLOPE * m;
    float sc = m * attS[c];
#pragma unroll
    for (int off = 1; off < 32; off <<= 1) sc += __shfl_xor(sc, off);
    float ex = __expf(sc);
    float num = ex * xl_s;
    float den = ex;
    int rs = rowptr[n], re = rowptr[n + 1];
    for (int base = rs; base < re; base += 32) {
      int cnt = min(32, re - base);
      int s_l = 0, e_l = 0;
      if (c < cnt) { s_l = csr_src[base + c]; e_l = csr_eid[base + c]; }
      for (int i = 0; i < cnt; ++i) {
        int s = __shfl(s_l, hbase + i);
        int eid = __shfl(e_l, hbase + i);
        float xlv = xl[(size_t)s * 32 + c];
        const float4* e4 = (const float4*)(ea + (size_t)eid * 16);
        float4 a0 = e4[0], a1 = e4[1], a2 = e4[2], a3 = e4[3];
        float ef2 = a0.x * weS[0 * 32 + c] + a0.y * weS[1 * 32 + c] +
                    a0.z * weS[2 * 32 + c] + a0.w * weS[3 * 32 + c] +
                    a1.x * weS[4 * 32 + c] + a1.y * weS[5 * 32 + c] +
                    a1.z * weS[6 * 32 + c] + a1.w * weS[7 * 32 + c] +
                    a2.x * weS[8 * 32 + c] + a2.y * weS[9 * 32 + c] +
                    a2.z * weS[10 * 32 + c] + a2.w * weS[11 * 32 + c] +
                    a3.x * weS[12 * 32 + c] + a3.y * weS[13 * 32 + c] +
                    a3.z * weS[14 * 32 + c] + a3.w * weS[15 * 32 + c];
        float mm = xlv + xr_v + ef2;
        mm = (mm > 0.f) ? mm : NEG_SLOPE * mm;
        float s2 = mm * attS[c];
#pragma unroll
        for (int off = 1; off < 32; off <<= 1) s2 += __shfl_xor(s2, off);
        float e2 = __expf(s2);
        num += e2 * xlv;
        den += e2;
      }
    }
    h[(size_t)n * 32 + c] = fmaxf(num / fmaxf(den, 1e-16f) + bS[c], 0.f);
  }
}

// ------------------------------------------------- fused mean-pool + fc
// batch is SORTED -> graph g owns a contiguous node range; one block per graph.
__global__ __launch_bounds__(256) void pool_fc_k(
    const float* __restrict__ h, const int* __restrict__ batch,
    const float* __restrict__ wfc, const float* __restrict__ bfc,
    float* __restrict__ out, int N) {
  int g = blockIdx.x;
  __shared__ int srange[2];
  __shared__ float part[8][32];
  int t = threadIdx.x;
  if (t < 2) {
    int key = g + t;                  // t==0: lower_bound(g), t==1: lower_bound(g+1)
    int lo = 0, hi = N;
    while (lo < hi) { int mid = (lo + hi) >> 1; if (batch[mid] < key) lo = mid + 1; else hi = mid; }
    srange[t] = lo;
  }
  __syncthreads();
  int rs = srange[0], re = srange[1];
  int c = t & 31, sub = t >> 5;       // 8 sub-groups of 32 channels
  float acc = 0.f;
  for (int n = rs + sub; n < re; n += 8) acc += h[(size_t)n * 32 + c];
  part[sub][c] = acc;
  __syncthreads();
  if (sub == 0) {
    float s = part[0][c];
#pragma unroll
    for (int i = 1; i < 8; ++i) s += part[i][c];
    part[0][c] = s / fmaxf((float)(re - rs), 1.f);
  }
  __syncthreads();
  if (sub == 0) {
    float a = 0.f;
#pragma unroll
    for (int k = 0; k < 32; ++k) a += part[0][k] * wfc[k * 32 + c];
    out[g * 32 + c] = a + bfc[c];
  }
}

// ----------------------------------------------------------------- launcher
extern "C" void kernel_launch(void* const* d_in, const int* in_sizes, int n_in,
                              void* d_out, int out_size, void* d_ws, size_t ws_size,
                              hipStream_t stream) {
  const float* x   = (const float*)d_in[0];
  const int*   ei  = (const int*)d_in[1];
  const float* ea  = (const float*)d_in[2];
  const int*   bat = (const int*)d_in[3];
  const float* wl1 = (const float*)d_in[4];
  const float* wr1 = (const float*)d_in[5];
  const float* we1 = (const float*)d_in[6];
  const float* at1 = (const float*)d_in[7];
  const float* b1  = (const float*)d_in[8];
  const float* wl2 = (const float*)d_in[9];
  const float* wr2 = (const float*)d_in[10];
  const float* we2 = (const float*)d_in[11];
  const float* at2 = (const float*)d_in[12];
  const float* b2  = (const float*)d_in[13];
  const float* wfc = (const float*)d_in[14];
  const float* bfc = (const float*)d_in[15];

  const int N = in_sizes[0] / 128;
  const int E = in_sizes[1] / 2;
  const int G = 256;
  const int* srcA = ei;
  const int* dstA = ei + E;

  // ---- workspace layout (~72 MB) ----
  int* deg      = (int*)d_ws;                  // N
  int* rowptr   = deg + N;                     // N+1
  int* cursor   = rowptr + (N + 1);            // N
  int* aux      = cursor + N;                  // 512
  int* csr_src  = aux + 512;                   // E
  int* csr_eid  = csr_src + E;                 // E
  float* loopA  = (float*)(csr_eid + E);       // N*16
  float* xl1    = loopA + (size_t)N * 16;      // N*64
  float* xr1    = xl1 + (size_t)N * 64;        // N*64
  float* h1     = xr1;                         // in-place over xr1
  float* xl2    = xl1;                         // N*32 (xl1 dead after gat1)
  float* xr2    = xl1 + (size_t)N * 32;        // N*32
  float* h2     = xr2;                         // in-place over xr2

  const int naux = (N + 255) / 256;

  // ---- CSR build ----
  zero_int_k<<<(N + 255) / 256, 256, 0, stream>>>(deg, N);
  deg_count_k<<<(E + 255) / 256, 256, 0, stream>>>(dstA, deg, E);
  scan1_k<<<naux, 256, 0, stream>>>(deg, rowptr, aux, N);
  scan2_k<<<1, 512, 0, stream>>>(aux, naux);
  scan3_k<<<(N + 256) / 256, 256, 0, stream>>>(rowptr, cursor, aux, N, E);
  scatter_k<<<(E + 255) / 256, 256, 0, stream>>>(srcA, dstA, cursor, csr_src, csr_eid, E);

  // ---- self-loop attrs ----
  loop_attr_k<<<(N * 16 + 255) / 256, 256, 0, stream>>>(rowptr, csr_eid, ea, loopA, N);

  // ---- layer 1 ----
  transform1_k<<<2048, 256, 0, stream>>>(x, wl1, wr1, xl1, xr1, N);
  gat1_k<<<8192, 256, 0, stream>>>(rowptr, csr_src, csr_eid, ea, loopA, we1, at1, b1,
                                   xl1, xr1, h1, N);

  // ---- layer 2 ----
  transform2_k<<<1024, 256, 0, stream>>>(h1, wl2, wr2, xl2, xr2, N);
  gat2_k<<<8192, 256, 0, stream>>>(rowptr, csr_src, csr_eid, ea, loopA, we2, at2, b2,
                                   xl2, xr2, h2, N);

  // ---- fused pool + fc ----
  pool_fc_k<<<G, 256, 0, stream>>>(h2, bat, wfc, bfc, (float*)d_out, N);
}